// Round 5
// baseline (666.646 us; speedup 1.0000x reference)
//
#include <hip/hip_runtime.h>
#include <hip/hip_fp16.h>
#include <math.h>
#include <type_traits>

#define BDIM 256
constexpr int Bb   = 8;
constexpr int C    = 512;
constexpr int T    = 4;
constexpr int HW   = 64 * 64;   // 4096
constexpr int NSP  = 100;
constexpr int DOUT = 128;
constexpr int CG   = 8;         // channels per K1 block
constexpr int NCG  = C / CG;    // 64 channel groups
constexpr int MT   = 16;        // rows per K2 block
constexpr int KC   = 32;        // K chunk in K2 (keeps LDS at 48 KiB)

// ---------------- K1: per-(b,t) segment means over 8 channels ----------------
// grid = B*T*NCG blocks. Cache 4096 ids in regs, stream 8 fp32 planes with
// float4 loads, LDS-atomic scatter into bins[8][100], divide, store means.
template <typename MeanT>
__global__ __launch_bounds__(BDIM) void seg_mean_kernel(
    const float* __restrict__ maps,   // (B,C,T,H,W) fp32
    const int*   __restrict__ mask,   // (B,T,H,W) int32
    MeanT*       __restrict__ mean_out) // (B*T, NSP, C)
{
    __shared__ float bins[CG * NSP];
    __shared__ float cnt[NSP];

    const int tid = threadIdx.x;
    const int bid = blockIdx.x;
    const int cg  = bid % NCG;       // channel group
    const int bt  = bid / NCG;       // b*T + t
    const int b   = bt / T, t = bt % T;

    for (int i = tid; i < CG * NSP; i += BDIM) bins[i] = 0.f;
    if (tid < NSP) cnt[tid] = 0.f;
    __syncthreads();

    // cache superpixel ids for this (b,t): 16 ids per thread in 4 int4
    const int4* mask4 = (const int4*)(mask + (size_t)bt * HW);
    int4 ids[4];
#pragma unroll
    for (int i = 0; i < 4; i++) ids[i] = mask4[i * BDIM + tid];

    // counts (once per block)
#pragma unroll
    for (int i = 0; i < 4; i++) {
        atomicAdd(&cnt[ids[i].x], 1.f);
        atomicAdd(&cnt[ids[i].y], 1.f);
        atomicAdd(&cnt[ids[i].z], 1.f);
        atomicAdd(&cnt[ids[i].w], 1.f);
    }

    // stream 8 channel planes (16 KiB each), scatter-add into LDS bins
    for (int cc = 0; cc < CG; cc++) {
        const int c = cg * CG + cc;
        const float4* plane =
            (const float4*)(maps + (((size_t)(b * C + c)) * T + t) * HW);
        float* bin = bins + cc * NSP;
#pragma unroll
        for (int i = 0; i < 4; i++) {
            float4 v = plane[i * BDIM + tid];
            atomicAdd(&bin[ids[i].x], v.x);
            atomicAdd(&bin[ids[i].y], v.y);
            atomicAdd(&bin[ids[i].z], v.z);
            atomicAdd(&bin[ids[i].w], v.w);
        }
    }
    __syncthreads();

    // flush means: 800 values per block
    for (int e = tid; e < CG * NSP; e += BDIM) {
        int cc = e / NSP, id = e % NSP;
        float cn = cnt[id];
        float m  = (cn > 0.f) ? bins[cc * NSP + id] / cn : 0.f;
        size_t idx = ((size_t)bt * NSP + id) * C + cg * CG + cc;
        if constexpr (std::is_same<MeanT, float>::value)
            mean_out[idx] = m;
        else
            mean_out[idx] = __float2half(m);
    }
}

// ------------- K2: FC (512->128) + L2 normalize + transpose, fused -----------
// grid = 3200/MT blocks. A tile (16x512) in LDS fp32; W transposed per 32-k
// chunk into Wt[k][d], ROW STRIDE = DOUT = 128 (d spans [0,128)!). Reads
// Wt[k*128 + lane] are 2-way bank-aliased -> free, no pad needed. Wave w owns
// rows 4w..4w+3; lane l owns cols l and l+64 -> per-row L2 norm is one 64-lane
// butterfly. fp32 output.
template <typename MeanT>
__global__ __launch_bounds__(BDIM) void fc_norm_kernel(
    const MeanT* __restrict__ A,    // (3200, 512) segment means
    const float* __restrict__ Wfc,  // (128, 512) fp32
    float*       __restrict__ out)  // (B, 128, T, NSP) fp32
{
    __shared__ float As[MT * C];        // 32 KiB
    __shared__ float Wt[KC * DOUT];     // 16 KiB, Wt[k*128 + d]

    const int tid  = threadIdx.x;
    const int row0 = blockIdx.x * MT;
    const int r0   = (tid >> 6) * 4;    // wave-uniform local row group
    const int c0   = tid & 63;          // output cols c0 and c0+64

    // stage A tile (coalesced)
    if constexpr (std::is_same<MeanT, float>::value) {
        const float4* Ag = (const float4*)(A + (size_t)row0 * C);
        float4* AsV = (float4*)As;
#pragma unroll
        for (int i = 0; i < (MT * C / 4) / BDIM; i++)
            AsV[tid + i * BDIM] = Ag[tid + i * BDIM];
    } else {
        const ushort4* Ag =
            (const ushort4*)((const unsigned short*)A + (size_t)row0 * C);
#pragma unroll
        for (int i = 0; i < (MT * C / 4) / BDIM; i++) {
            ushort4 h = Ag[tid + i * BDIM];
            int base = (tid + i * BDIM) * 4;
            As[base + 0] = __half2float(*(const __half*)&h.x);
            As[base + 1] = __half2float(*(const __half*)&h.y);
            As[base + 2] = __half2float(*(const __half*)&h.z);
            As[base + 3] = __half2float(*(const __half*)&h.w);
        }
    }

    float acc[4][2] = {};

    for (int kc = 0; kc < C / KC; kc++) {
        __syncthreads();   // prev-chunk Wt readers done; covers As on kc==0
        // stage transposed W chunk: Wt[k][d], k in [kc*KC, kc*KC+KC)
#pragma unroll
        for (int i = 0; i < (DOUT * KC / 4) / BDIM; i++) {
            int f  = tid + i * BDIM;        // 0..1023
            int d  = f >> 3;                // 0..127
            int k4 = f & 7;                 // 0..7
            float4 w = *(const float4*)(Wfc + (size_t)d * C + kc * KC + k4 * 4);
            Wt[(k4 * 4 + 0) * DOUT + d] = w.x;
            Wt[(k4 * 4 + 1) * DOUT + d] = w.y;
            Wt[(k4 * 4 + 2) * DOUT + d] = w.z;
            Wt[(k4 * 4 + 3) * DOUT + d] = w.w;
        }
        __syncthreads();

#pragma unroll
        for (int k4 = 0; k4 < KC / 4; k4++) {
            float4 a[4];
#pragma unroll
            for (int i = 0; i < 4; i++)   // wave-uniform broadcast reads
                a[i] = *(const float4*)&As[(r0 + i) * C + kc * KC + k4 * 4];
#pragma unroll
            for (int j = 0; j < 4; j++) {
                float w0 = Wt[(k4 * 4 + j) * DOUT + c0];
                float w1 = Wt[(k4 * 4 + j) * DOUT + c0 + 64];
#pragma unroll
                for (int i = 0; i < 4; i++) {
                    float av = (j == 0) ? a[i].x : (j == 1) ? a[i].y
                             : (j == 2) ? a[i].z : a[i].w;
                    acc[i][0] = fmaf(av, w0, acc[i][0]);
                    acc[i][1] = fmaf(av, w1, acc[i][1]);
                }
            }
        }
    }

    // epilogue: per-row L2 norm over 128 cols == 64-lane butterfly (2 cols/lane)
#pragma unroll
    for (int i = 0; i < 4; i++) {
        float ss = acc[i][0] * acc[i][0] + acc[i][1] * acc[i][1];
#pragma unroll
        for (int off = 32; off > 0; off >>= 1)
            ss += __shfl_xor(ss, off, 64);
        float inv = 1.f / fmaxf(sqrtf(ss), 1e-12f);

        int row = row0 + r0 + i;         // (b*T+t)*100 + n
        int n   = row % NSP;
        int bt  = row / NSP;
        int b   = bt >> 2, t = bt & 3;
        out[(((size_t)b * DOUT + c0)      * T + t) * NSP + n] = acc[i][0] * inv;
        out[(((size_t)b * DOUT + c0 + 64) * T + t) * NSP + n] = acc[i][1] * inv;
    }
}

extern "C" void kernel_launch(void* const* d_in, const int* in_sizes, int n_in,
                              void* d_out, int out_size, void* d_ws, size_t ws_size,
                              hipStream_t stream) {
    // Identify inputs by SIZE RANK (robust to ordering):
    // maps (67.1M el) > sp_mask (131K el) > W_fc (65.5K el) > scalar (1).
    int iMaps = 0, iMask = 1, iW = 2;
    {
        long best = -1;
        for (int i = 0; i < n_in; i++)
            if ((long)in_sizes[i] > best) { best = in_sizes[i]; iMaps = i; }
        long b2 = -1;
        for (int i = 0; i < n_in; i++)
            if (i != iMaps && (long)in_sizes[i] > b2) { b2 = in_sizes[i]; iMask = i; }
        long b3 = -1;
        for (int i = 0; i < n_in; i++)
            if (i != iMaps && i != iMask && (long)in_sizes[i] > b3) { b3 = in_sizes[i]; iW = i; }
    }
    const float* maps = (const float*)d_in[iMaps];  // fp32
    const int*   mask = (const int*)d_in[iMask];    // int32
    const float* Wfc  = (const float*)d_in[iW];     // fp32
    float*       out  = (float*)d_out;              // fp32 (reference dtype)

    const dim3 g1(Bb * T * NCG), g2(Bb * T * NSP / MT), blk(BDIM);
    const size_t need_f32 = (size_t)Bb * T * NSP * C * sizeof(float);   // 6.55 MB

    if (ws_size >= need_f32) {
        float* mean_ws = (float*)d_ws;
        seg_mean_kernel<float><<<g1, blk, 0, stream>>>(maps, mask, mean_ws);
        fc_norm_kernel<float><<<g2, blk, 0, stream>>>(mean_ws, Wfc, out);
    } else {
        // fallback: fp16 means (3.28 MB) — ~5e-4 rel err, threshold is 2%
        __half* mean_ws = (__half*)d_ws;
        seg_mean_kernel<__half><<<g1, blk, 0, stream>>>(maps, mask, mean_ws);
        fc_norm_kernel<__half><<<g2, blk, 0, stream>>>(mean_ws, Wfc, out);
    }
}